// Round 7
// baseline (229.486 us; speedup 1.0000x reference)
//
#include <hip/hip_runtime.h>

typedef __attribute__((ext_vector_type(8))) short    v8s;   // 8 bf16 (4 VGPR)
typedef __attribute__((ext_vector_type(4))) float    f4;
typedef __attribute__((ext_vector_type(2))) float    f2;
typedef __attribute__((ext_vector_type(2))) unsigned u32x2;

#define MFMA16 __builtin_amdgcn_mfma_f32_16x16x32_bf16

// ---- d_ws layout ----
// bf16 section (ushort units)
#define AW1T 0        // [64][128]
#define TW1T 8192
#define CW1T 16384
#define AW2T 24576    // [64][64]
#define TW2T 28672
#define CW2T 32768
#define MWT  36864    // [16][64] rows 8..15 zero
#define HWT  37888    // [48][64] rows diag-first-permuted, 36..47 zero
#define FW1XT 40960   // + i*4096 : [32][128]
#define FW2T  57344   // + i*512  : [16][32] rows 8..15 zero
#define WS_BF16_TOTAL 59392
// f32 section (float units, base = d_ws + WS_BF16_TOTAL*2)
#define W1CTO 0       // + i*128 : [32][4]  (cond weights, row=neuron, k=0..3)
#define HBPO  512     // [48] hb permuted

#define LOG2PI 1.83787706640934548356f
#define EPSF   1.1920928955078125e-07f

__device__ __constant__ int PERM[36] = {0,2,5,9,14,20,27,35,
  1,3,4,6,7,8,10,11,12,13,15,16,17,18,19,21,22,23,24,25,26,28,29,30,31,32,33,34};

__device__ __forceinline__ float ubits(unsigned u){union{unsigned u;float f;}c;c.u=u;return c.f;}
__device__ __forceinline__ unsigned fbits(float f){union{float f;unsigned u;}c;c.f=f;return c.u;}
__device__ __forceinline__ float siluf(float v){ return v/(1.f+__expf(-v)); }
__device__ __forceinline__ unsigned pk2(float a,float b){            // 2x f32 -> packed bf16 (RTNE)
  unsigned ua=fbits(a); ua+=0x7fffu+((ua>>16)&1u);
  unsigned ub=fbits(b); ub+=0x7fffu+((ub>>16)&1u);
  return (ua>>16)|(ub&0xffff0000u);
}
__device__ __forceinline__ unsigned short f2bu(float a){
  unsigned ua=fbits(a); ua+=0x7fffu+((ua>>16)&1u);
  return (unsigned short)(ua>>16);
}
__device__ __forceinline__ float qsum(float v){                       // sum over the 4 quads
  v += __shfl_xor(v,16,64); v += __shfl_xor(v,32,64); return v;
}

// ============ prep: transpose/pad/permute weights into ws (bf16) ============
__global__ __launch_bounds__(256)
void prep_kernel(const float* __restrict__ aW1, const float* __restrict__ aW2,
                 const float* __restrict__ mW,  const float* __restrict__ tW1,
                 const float* __restrict__ tW2, const float* __restrict__ hW,
                 const float* __restrict__ hb,  const float* __restrict__ cW1,
                 const float* __restrict__ cW2, const float* __restrict__ fW1,
                 const float* __restrict__ fW2,
                 unsigned short* __restrict__ ws16, float* __restrict__ wsf)
{
  const int tid = blockIdx.x*256 + threadIdx.x;
  const int stride = gridDim.x*256;
  for (int idx=tid; idx<64*128; idx+=stride){        // [n][k] <- [k][n]
    int n=idx>>7, k=idx&127;
    ws16[AW1T+idx]=f2bu(aW1[k*64+n]);
    ws16[TW1T+idx]=f2bu(tW1[k*64+n]);
    ws16[CW1T+idx]=f2bu(cW1[k*64+n]);
  }
  for (int idx=tid; idx<64*64; idx+=stride){
    int n=idx>>6, k=idx&63;
    ws16[AW2T+idx]=f2bu(aW2[k*64+n]);
    ws16[TW2T+idx]=f2bu(tW2[k*64+n]);
    ws16[CW2T+idx]=f2bu(cW2[k*64+n]);
  }
  for (int idx=tid; idx<16*64; idx+=stride){
    int n=idx>>6, k=idx&63;
    ws16[MWT+idx]=f2bu(n<8 ? mW[k*8+n] : 0.f);
  }
  for (int idx=tid; idx<48*64; idx+=stride){         // diag-first row permutation
    int n=idx>>6, k=idx&63;
    ws16[HWT+idx]=f2bu(n<36 ? hW[k*36+PERM[n]] : 0.f);
  }
  for (int idx=tid; idx<4*32*128; idx+=stride){      // fW1 x-part
    int i=idx>>12, rem=idx&4095, n=rem>>7, k=rem&127;
    ws16[FW1XT+idx]=f2bu(fW1[i*4224 + (4+k)*32 + n]);
  }
  for (int idx=tid; idx<4*16*32; idx+=stride){
    int i=idx>>9, rem=idx&511, n=rem>>5, k=rem&31;
    ws16[FW2T+idx]=f2bu(n<8 ? fW2[i*256 + k*8 + n] : 0.f);
  }
  for (int idx=tid; idx<4*32*4; idx+=stride){        // fW1 cond part, fp32 [n][k]
    int i=idx>>7, rem=idx&127, n=rem>>2, k=rem&3;
    wsf[W1CTO+idx]=fW1[i*4224 + k*32 + n];
  }
  for (int idx=tid; idx<48; idx+=stride)
    wsf[HBPO+idx] = idx<36 ? hb[PERM[idx]] : 0.f;
}

// ============ GEMM helpers (outputs transposed: rows=neurons, cols=elems) ===
template<int NWT, int NET>
__device__ __forceinline__ void gemmX(const unsigned short* __restrict__ Wt,
                                      const v8s* __restrict__ xf,
                                      f4 (*acc)[NET], int c, int q)
{
#pragma unroll
  for (int kt=0; kt<4; ++kt){
    v8s wf[NWT];
#pragma unroll
    for (int wt=0; wt<NWT; ++wt)
      wf[wt] = *(const v8s*)(Wt + (wt*16 + c)*128 + kt*32 + q*8);
#pragma unroll
    for (int wt=0; wt<NWT; ++wt)
#pragma unroll
      for (int et=0; et<NET; ++et)
        acc[wt][et] = MFMA16(wf[wt], xf[et*4+kt], acc[wt][et], 0,0,0);
  }
}

template<int NWT, int NET>
__device__ __forceinline__ void gemmH(const unsigned short* __restrict__ Wt,
                                      const unsigned short* __restrict__ actL,
                                      f4 (*acc)[NET], int c, int q)
{
#pragma unroll
  for (int kt=0; kt<2; ++kt){
    v8s wf[NWT];
#pragma unroll
    for (int wt=0; wt<NWT; ++wt)
      wf[wt] = *(const v8s*)(Wt + (wt*16 + c)*64 + kt*32 + q*8);
    v8s af[NET];
#pragma unroll
    for (int et=0; et<NET; ++et)
      af[et] = *(const v8s*)(actL + (et*16+c)*72 + kt*32 + q*8);
#pragma unroll
    for (int wt=0; wt<NWT; ++wt)
#pragma unroll
      for (int et=0; et<NET; ++et)
        acc[wt][et] = MFMA16(wf[wt], af[et], acc[wt][et], 0,0,0);
  }
}

// ============ main: 32 elements per wave (et=0..1), 1 wave/block ============
__global__ __launch_bounds__(64,4)
void policy_kernel(
    const float* __restrict__ x,    const float* __restrict__ action, const float* __restrict__ z_rpo,
    const float* __restrict__ cb1,  const float* __restrict__ c_rms,  const float* __restrict__ cb2,
    const float* __restrict__ cW3,  const float* __restrict__ cb3,
    const float* __restrict__ ab1,  const float* __restrict__ ab2,    const float* __restrict__ mb,
    const float* __restrict__ tb1,  const float* __restrict__ t_rms1, const float* __restrict__ tb2,
    const float* __restrict__ t_rms2,
    const float* __restrict__ fb1,  const float* __restrict__ fb2,
    const unsigned short* __restrict__ ws16, const float* __restrict__ wsf,
    float* __restrict__ out, const int Btot)
{
  const int lane = threadIdx.x;
  const int q = lane >> 4, c = lane & 15;
  const int b0 = blockIdx.x << 5;                    // 32 elements per block

  __shared__ alignas(16) unsigned char smem[9984];
  unsigned short* actL = (unsigned short*)smem;            // [32][72] bf16 (flow: hidL [32][40])
  unsigned short* hidL = (unsigned short*)smem;
  unsigned short* triL = (unsigned short*)(smem + 4608);   // [32][44] bf16
  float*          nstL = (float*)(smem + 7424);            // [32][10]
  float*          amL  = (float*)(smem + 8704);            // [32][10] (st aliases)

  // ---- resident x fragments: xf[et*4+kt] = x[et*16+c][kt*32+q*8 ..+8] ----
  v8s xf[8];
  {
    const float* xb = x + (size_t)b0*128;
#pragma unroll
    for (int et=0; et<2; ++et)
#pragma unroll
      for (int kt=0; kt<4; ++kt){
        const float* p = xb + (size_t)(et*16+c)*128 + kt*32 + q*8;
        f4 u0 = *(const f4*)p, u1 = *(const f4*)(p+4);
        union { unsigned u[4]; v8s v; } r;
        r.u[0]=pk2(u0[0],u0[1]); r.u[1]=pk2(u0[2],u0[3]);
        r.u[2]=pk2(u1[0],u1[1]); r.u[3]=pk2(u1[2],u1[3]);
        xf[et*4+kt] = r.v;
      }
  }

  f4 acc[4][2];
  const f4 z4 = {0.f,0.f,0.f,0.f};

  // =================== actor ===================
#pragma unroll
  for (int wt=0; wt<4; ++wt) for (int et=0; et<2; ++et) acc[wt][et]=z4;
  gemmX<4,2>(ws16+AW1T, xf, acc, c, q);
#pragma unroll
  for (int wt=0; wt<4; ++wt){
    const f4 bv = *(const f4*)(ab1 + wt*16 + q*4);
#pragma unroll
    for (int et=0; et<2; ++et){
      float s0=siluf(acc[wt][et][0]+bv[0]), s1=siluf(acc[wt][et][1]+bv[1]);
      float s2=siluf(acc[wt][et][2]+bv[2]), s3=siluf(acc[wt][et][3]+bv[3]);
      u32x2 u = {pk2(s0,s1), pk2(s2,s3)};
      *(u32x2*)(actL + (et*16+c)*72 + wt*16 + q*4) = u;
    }
  }
#pragma unroll
  for (int wt=0; wt<4; ++wt) for (int et=0; et<2; ++et) acc[wt][et]=z4;
  gemmH<4,2>(ws16+AW2T, actL, acc, c, q);
#pragma unroll
  for (int wt=0; wt<4; ++wt){
    const f4 bv = *(const f4*)(ab2 + wt*16 + q*4);
#pragma unroll
    for (int et=0; et<2; ++et){
      float s0=siluf(acc[wt][et][0]+bv[0]), s1=siluf(acc[wt][et][1]+bv[1]);
      float s2=siluf(acc[wt][et][2]+bv[2]), s3=siluf(acc[wt][et][3]+bv[3]);
      u32x2 u = {pk2(s0,s1), pk2(s2,s3)};
      *(u32x2*)(actL + (et*16+c)*72 + wt*16 + q*4) = u;
    }
  }
  {
    f4 am1[1][2]; am1[0][0]=z4; am1[0][1]=z4;
    gemmH<1,2>(ws16+MWT, actL, am1, c, q);
    if (q<2){
      const f4 mbv = *(const f4*)(mb + q*4);
#pragma unroll
      for (int et=0; et<2; ++et){
        float* p = amL + (et*16+c)*10 + q*4;
        *(f2*)p     = (f2){am1[0][et][0]+mbv[0], am1[0][et][1]+mbv[1]};
        *(f2*)(p+2) = (f2){am1[0][et][2]+mbv[2], am1[0][et][3]+mbv[3]};
      }
    }
  }

  // =================== t branch ===================
#pragma unroll
  for (int wt=0; wt<4; ++wt) for (int et=0; et<2; ++et) acc[wt][et]=z4;
  gemmX<4,2>(ws16+TW1T, xf, acc, c, q);
  float r1[2];
  {
    float ss[2]={0.f,0.f};
#pragma unroll
    for (int wt=0; wt<4; ++wt){
      const f4 bv = *(const f4*)(tb1 + wt*16 + q*4);
      const f4 rw = *(const f4*)(t_rms1 + wt*16 + q*4);
#pragma unroll
      for (int et=0; et<2; ++et){
        float s0=siluf(acc[wt][et][0]+bv[0]), s1=siluf(acc[wt][et][1]+bv[1]);
        float s2=siluf(acc[wt][et][2]+bv[2]), s3=siluf(acc[wt][et][3]+bv[3]);
        ss[et] += s0*s0+s1*s1+s2*s2+s3*s3;
        u32x2 u = {pk2(s0*rw[0],s1*rw[1]), pk2(s2*rw[2],s3*rw[3])};
        *(u32x2*)(actL + (et*16+c)*72 + wt*16 + q*4) = u;
      }
    }
#pragma unroll
    for (int et=0; et<2; ++et) r1[et]=rsqrtf(qsum(ss[et])*(1.f/64.f)+EPSF);
  }
#pragma unroll
  for (int wt=0; wt<4; ++wt) for (int et=0; et<2; ++et) acc[wt][et]=z4;
  gemmH<4,2>(ws16+TW2T, actL, acc, c, q);
  float r2[2];
  {
    float ss[2]={0.f,0.f};
#pragma unroll
    for (int wt=0; wt<4; ++wt){
      const f4 bv = *(const f4*)(tb2 + wt*16 + q*4);
      const f4 rw = *(const f4*)(t_rms2 + wt*16 + q*4);
#pragma unroll
      for (int et=0; et<2; ++et){
        float s0=siluf(r1[et]*acc[wt][et][0]+bv[0]), s1=siluf(r1[et]*acc[wt][et][1]+bv[1]);
        float s2=siluf(r1[et]*acc[wt][et][2]+bv[2]), s3=siluf(r1[et]*acc[wt][et][3]+bv[3]);
        ss[et] += s0*s0+s1*s1+s2*s2+s3*s3;
        u32x2 u = {pk2(s0*rw[0],s1*rw[1]), pk2(s2*rw[2],s3*rw[3])};
        *(u32x2*)(actL + (et*16+c)*72 + wt*16 + q*4) = u;
      }
    }
#pragma unroll
    for (int et=0; et<2; ++et) r2[et]=rsqrtf(qsum(ss[et])*(1.f/64.f)+EPSF);
  }
  // Cholesky head (rows permuted diag-first; diag = rows 0..7 = wt0, q<2)
  float ldet[2];
  {
    f4 a3[3][2];
#pragma unroll
    for (int wt=0; wt<3; ++wt) for (int et=0; et<2; ++et) a3[wt][et]=z4;
    gemmH<3,2>(ws16+HWT, actL, a3, c, q);
    float ldp[2]={0.f,0.f};
#pragma unroll
    for (int wt=0; wt<3; ++wt){
      const f4 hbv = *(const f4*)(wsf + HBPO + wt*16 + q*4);
#pragma unroll
      for (int et=0; et<2; ++et){
        float t0=r2[et]*a3[wt][et][0]+hbv[0], t1=r2[et]*a3[wt][et][1]+hbv[1];
        float t2=r2[et]*a3[wt][et][2]+hbv[2], t3=r2[et]*a3[wt][et][3]+hbv[3];
        if (wt==0 && q<2){
          t0=fmaxf(t0,0.f)+__logf(1.f+__expf(-fabsf(t0)));
          t1=fmaxf(t1,0.f)+__logf(1.f+__expf(-fabsf(t1)));
          t2=fmaxf(t2,0.f)+__logf(1.f+__expf(-fabsf(t2)));
          t3=fmaxf(t3,0.f)+__logf(1.f+__expf(-fabsf(t3)));
          ldp[et] += __logf(t0)+__logf(t1)+__logf(t2)+__logf(t3);
        }
        if (wt<2 || q==0){
          u32x2 u = {pk2(t0,t1), pk2(t2,t3)};
          *(u32x2*)(triL + (et*16+c)*44 + wt*16 + q*4) = u;
        }
      }
    }
#pragma unroll
    for (int et=0; et<2; ++et) ldet[et]=qsum(ldp[et]);
  }

  // =================== critic ===================
#pragma unroll
  for (int wt=0; wt<4; ++wt) for (int et=0; et<2; ++et) acc[wt][et]=z4;
  gemmX<4,2>(ws16+CW1T, xf, acc, c, q);
  float rc[2];
  {
    float ss[2]={0.f,0.f};
#pragma unroll
    for (int wt=0; wt<4; ++wt){
      const f4 bv = *(const f4*)(cb1 + wt*16 + q*4);
      const f4 rw = *(const f4*)(c_rms + wt*16 + q*4);
#pragma unroll
      for (int et=0; et<2; ++et){
        float s0=siluf(acc[wt][et][0]+bv[0]), s1=siluf(acc[wt][et][1]+bv[1]);
        float s2=siluf(acc[wt][et][2]+bv[2]), s3=siluf(acc[wt][et][3]+bv[3]);
        ss[et] += s0*s0+s1*s1+s2*s2+s3*s3;
        u32x2 u = {pk2(s0*rw[0],s1*rw[1]), pk2(s2*rw[2],s3*rw[3])};
        *(u32x2*)(actL + (et*16+c)*72 + wt*16 + q*4) = u;
      }
    }
#pragma unroll
    for (int et=0; et<2; ++et) rc[et]=rsqrtf(qsum(ss[et])*(1.f/64.f)+EPSF);
  }
  float vv[2];
  {
#pragma unroll
    for (int wt=0; wt<4; ++wt) for (int et=0; et<2; ++et) acc[wt][et]=z4;
    gemmH<4,2>(ws16+CW2T, actL, acc, c, q);
    float vp[2]={0.f,0.f};
#pragma unroll
    for (int wt=0; wt<4; ++wt){
      const f4 bv = *(const f4*)(cb2 + wt*16 + q*4);
      const f4 wv = *(const f4*)(cW3 + wt*16 + q*4);
#pragma unroll
      for (int et=0; et<2; ++et){
        vp[et] = fmaf(siluf(rc[et]*acc[wt][et][0]+bv[0]), wv[0], vp[et]);
        vp[et] = fmaf(siluf(rc[et]*acc[wt][et][1]+bv[1]), wv[1], vp[et]);
        vp[et] = fmaf(siluf(rc[et]*acc[wt][et][2]+bv[2]), wv[2], vp[et]);
        vp[et] = fmaf(siluf(rc[et]*acc[wt][et][3]+bv[3]), wv[3], vp[et]);
      }
    }
    const float cb3v = cb3[0];
#pragma unroll
    for (int et=0; et<2; ++et) vv[et]=qsum(vp[et])+cb3v;
  }

  // ============ per-element: nst, action passthrough (lanes 0..31) ============
  const int l = lane;
  float nst[8], fld=0.f;
  if (l < 32) {
    const size_t bb = (size_t)(b0+l)*8;
    f4 a0=*(const f4*)(action+bb), a1=*(const f4*)(action+bb+4);
    f4 zr0=*(const f4*)(z_rpo+bb), zr1=*(const f4*)(z_rpo+bb+4);
    *(f4*)(out+bb)=a0; *(f4*)(out+bb+4)=a1;
#pragma unroll
    for (int j=0;j<4;++j){
      nst[j]   = a0[j]-amL[l*10+j]  -zr0[j];
      nst[4+j] = a1[j]-amL[l*10+4+j]-zr1[j];
    }
#pragma unroll
    for (int j=0;j<8;++j) nstL[l*10+j]=nst[j];
  }

  // ======= flow (hidL aliases actL; stL aliases amL); GEMMs all-lane =======
#pragma unroll
  for (int ii=0; ii<4; ++ii){
    const int i = 3-ii;
    const int cb = (i&1)?4:0, yb = (i&1)?0:4;
    f4 a2[2][2];
#pragma unroll
    for (int wt=0; wt<2; ++wt) for (int et=0; et<2; ++et) a2[wt][et]=z4;
    gemmX<2,2>(ws16+FW1XT+i*4096, xf, a2, c, q);
    float nv[2][4];
#pragma unroll
    for (int et=0; et<2; ++et){
      const float* np = nstL + (et*16+c)*10 + cb;
      f2 t0=*(const f2*)np, t1=*(const f2*)(np+2);
      nv[et][0]=t0[0]; nv[et][1]=t0[1]; nv[et][2]=t1[0]; nv[et][3]=t1[1];
    }
#pragma unroll
    for (int wt=0; wt<2; ++wt){
      const f4 bv = *(const f4*)(fb1 + i*32 + wt*16 + q*4);
      float sh[2][4];
#pragma unroll
      for (int r=0; r<4; ++r){
        const f4 wc = *(const f4*)(wsf + W1CTO + i*128 + (wt*16+q*4+r)*4);
#pragma unroll
        for (int et=0; et<2; ++et){
          float hv = a2[wt][et][r] + bv[r]
                   + wc[0]*nv[et][0] + wc[1]*nv[et][1]
                   + wc[2]*nv[et][2] + wc[3]*nv[et][3];
          sh[et][r] = siluf(hv);
        }
      }
#pragma unroll
      for (int et=0; et<2; ++et){
        u32x2 u = {pk2(sh[et][0],sh[et][1]), pk2(sh[et][2],sh[et][3])};
        *(u32x2*)(hidL + (et*16+c)*40 + wt*16 + q*4) = u;
      }
    }
    // second flow layer: st = silu(hid) @ fW2 + fb2
    {
      const v8s wf3 = *(const v8s*)(ws16 + FW2T + i*512 + c*32 + q*8);
      f4 as[2];
#pragma unroll
      for (int et=0; et<2; ++et){
        const v8s hf = *(const v8s*)(hidL + (et*16+c)*40 + q*8);
        f4 a1s = z4;
        a1s = MFMA16(wf3, hf, a1s, 0,0,0);
        as[et]=a1s;
      }
      if (q<2){
        const f4 fbv = *(const f4*)(fb2 + i*8 + q*4);
#pragma unroll
        for (int et=0; et<2; ++et){
          float* p = amL + (et*16+c)*10 + q*4;   // stL
          *(f2*)p     = (f2){as[et][0]+fbv[0], as[et][1]+fbv[1]};
          *(f2*)(p+2) = (f2){as[et][2]+fbv[2], as[et][3]+fbv[3]};
        }
      }
    }
    // per-element update (lanes 0..31)
    if (l < 32) {
      float sr0=amL[l*10+0], sr1=amL[l*10+1], sr2=amL[l*10+2], sr3=amL[l*10+3];
      float th0=amL[l*10+4], th1=amL[l*10+5], th2=amL[l*10+6], th3=amL[l*10+7];
      float s0=2.f-4.f/(__expf(2.f*sr0)+1.f);
      float s1=2.f-4.f/(__expf(2.f*sr1)+1.f);
      float s2=2.f-4.f/(__expf(2.f*sr2)+1.f);
      float s3=2.f-4.f/(__expf(2.f*sr3)+1.f);
      nst[yb+0]=(nst[yb+0]-th0)*__expf(-s0);
      nst[yb+1]=(nst[yb+1]-th1)*__expf(-s1);
      nst[yb+2]=(nst[yb+2]-th2)*__expf(-s2);
      nst[yb+3]=(nst[yb+3]-th3)*__expf(-s3);
      nstL[l*10+yb+0]=nst[yb+0]; nstL[l*10+yb+1]=nst[yb+1];
      nstL[l*10+yb+2]=nst[yb+2]; nstL[l*10+yb+3]=nst[yb+3];
      fld += s0+s1+s2+s3;
    }
  }

  // =================== triangular solve + outputs (lanes 0..31) ===================
  if (l < 32) {
    constexpr int INVPERM[36] = {0,8,1,9,10,2,11,12,13,3,14,15,16,17,4,18,19,20,
                                 21,22,5,23,24,25,26,27,28,6,29,30,31,32,33,34,35,7};
    float tri[36];
#pragma unroll
    for (int j=0;j<36;++j){
      unsigned h = triL[l*44 + INVPERM[j]];
      tri[j] = ubits(h<<16);
    }
    float zv[8], mahal=0.f;
#pragma unroll
    for (int r=0;r<8;++r){
      float s=nst[r];
      const int base=(r*(r+1))>>1;
#pragma unroll
      for (int cc=0;cc<r;++cc) s -= tri[base+cc]*zv[cc];
      const float z = s/tri[base+r];
      zv[r]=z; mahal+=z*z;
    }
    const float ldet_s = (l<16)?ldet[0]:ldet[1];
    const float v_s    = (l<16)?vv[0]:vv[1];
    const float lp = -0.5f*(8.f*LOG2PI+mahal) - ldet_s - fld;
    const float en =  0.5f*(8.f*(1.f+LOG2PI)) + ldet_s + fld;
    out[(size_t)Btot*8  + b0 + l] = lp;
    out[(size_t)Btot*9  + b0 + l] = en;
    out[(size_t)Btot*10 + b0 + l] = v_s;
  }
}

extern "C" void kernel_launch(void* const* d_in, const int* in_sizes, int n_in,
                              void* d_out, int out_size, void* d_ws, size_t ws_size,
                              hipStream_t stream) {
  const float* x      = (const float*)d_in[0];
  const float* action = (const float*)d_in[1];
  const float* z_rpo  = (const float*)d_in[2];
  const float* cW1    = (const float*)d_in[3];
  const float* cb1    = (const float*)d_in[4];
  const float* c_rms  = (const float*)d_in[5];
  const float* cW2    = (const float*)d_in[6];
  const float* cb2    = (const float*)d_in[7];
  const float* cW3    = (const float*)d_in[8];
  const float* cb3    = (const float*)d_in[9];
  const float* aW1    = (const float*)d_in[10];
  const float* ab1    = (const float*)d_in[11];
  const float* aW2    = (const float*)d_in[12];
  const float* ab2    = (const float*)d_in[13];
  const float* mW     = (const float*)d_in[14];
  const float* mb     = (const float*)d_in[15];
  const float* tW1    = (const float*)d_in[16];
  const float* tb1    = (const float*)d_in[17];
  const float* t_rms1 = (const float*)d_in[18];
  const float* tW2    = (const float*)d_in[19];
  const float* tb2    = (const float*)d_in[20];
  const float* t_rms2 = (const float*)d_in[21];
  const float* hW     = (const float*)d_in[22];
  const float* hb     = (const float*)d_in[23];
  const float* fW1    = (const float*)d_in[24];
  const float* fb1    = (const float*)d_in[25];
  const float* fW2    = (const float*)d_in[26];
  const float* fb2    = (const float*)d_in[27];
  float* out = (float*)d_out;

  unsigned short* ws16 = (unsigned short*)d_ws;
  float* wsf = (float*)((char*)d_ws + WS_BF16_TOTAL*2);

  const int Btot = in_sizes[0] / 128;   // 131072

  hipLaunchKernelGGL(prep_kernel, dim3(128), dim3(256), 0, stream,
                     aW1, aW2, mW, tW1, tW2, hW, hb, cW1, cW2, fW1, fW2, ws16, wsf);
  hipLaunchKernelGGL(policy_kernel, dim3(Btot/32), dim3(64), 0, stream,
                     x, action, z_rpo, cb1, c_rms, cb2, cW3, cb3,
                     ab1, ab2, mb, tb1, t_rms1, tb2, t_rms2, fb1, fb2,
                     ws16, wsf, out, Btot);
}

// Round 8
// 212.683 us; speedup vs baseline: 1.0790x; 1.0790x over previous
//
#include <hip/hip_runtime.h>

typedef __attribute__((ext_vector_type(8))) short    v8s;   // 8 bf16 (4 VGPR)
typedef __attribute__((ext_vector_type(4))) float    f4;
typedef __attribute__((ext_vector_type(2))) float    f2;
typedef __attribute__((ext_vector_type(2))) unsigned u32x2;

#define MFMA16 __builtin_amdgcn_mfma_f32_16x16x32_bf16

// ---- d_ws layout ----
// bf16 section (ushort units)
#define AW1T 0        // [64][128]
#define TW1T 8192
#define CW1T 16384
#define AW2T 24576    // [64][64]
#define TW2T 28672
#define CW2T 32768
#define MWT  36864    // [16][64] rows 8..15 zero
#define HWT  37888    // [48][64] rows diag-first-permuted, 36..47 zero
#define FW1XT 40960   // + i*4096 : [32][128]
#define FW2T  57344   // + i*512  : [16][32] rows 8..15 zero
#define WS_BF16_TOTAL 59392
// f32 section (float units, base = d_ws + WS_BF16_TOTAL*2)
#define W1CTO 0       // + i*128 : [32][4]  (cond weights, row=neuron, k=0..3)
#define HBPO  512     // [48] hb permuted

#define LOG2PI 1.83787706640934548356f
#define EPSF   1.1920928955078125e-07f

__device__ __constant__ int PERM[36] = {0,2,5,9,14,20,27,35,
  1,3,4,6,7,8,10,11,12,13,15,16,17,18,19,21,22,23,24,25,26,28,29,30,31,32,33,34};

__device__ __forceinline__ float ubits(unsigned u){union{unsigned u;float f;}c;c.u=u;return c.f;}
__device__ __forceinline__ unsigned fbits(float f){union{float f;unsigned u;}c;c.f=f;return c.u;}
__device__ __forceinline__ float rcpf(float x){ return __builtin_amdgcn_rcpf(x); }
__device__ __forceinline__ float siluf(float v){ return v * rcpf(1.f + __expf(-v)); }
__device__ __forceinline__ unsigned pk2(float a,float b){            // 2x f32 -> packed bf16 (RTNE)
  unsigned ua=fbits(a); ua+=0x7fffu+((ua>>16)&1u);
  unsigned ub=fbits(b); ub+=0x7fffu+((ub>>16)&1u);
  return (ua>>16)|(ub&0xffff0000u);
}
__device__ __forceinline__ unsigned short f2bu(float a){
  unsigned ua=fbits(a); ua+=0x7fffu+((ua>>16)&1u);
  return (unsigned short)(ua>>16);
}
__device__ __forceinline__ float b2f16(unsigned short h){ return ubits(((unsigned)h)<<16); }
__device__ __forceinline__ float qsum(float v){                       // sum over the 4 quads
  v += __shfl_xor(v,16,64); v += __shfl_xor(v,32,64); return v;
}
// XOR-swizzled halfword offset into a [64][64]-bf16 tile: 16B blocks swizzled by row&7
__device__ __forceinline__ int swz(int row, int blk){ return row*64 + ((blk ^ (row&7))*8); }

// ============ prep: transpose/pad/permute weights into ws (bf16) ============
__global__ __launch_bounds__(256)
void prep_kernel(const float* __restrict__ aW1, const float* __restrict__ aW2,
                 const float* __restrict__ mW,  const float* __restrict__ tW1,
                 const float* __restrict__ tW2, const float* __restrict__ hW,
                 const float* __restrict__ hb,  const float* __restrict__ cW1,
                 const float* __restrict__ cW2, const float* __restrict__ fW1,
                 const float* __restrict__ fW2,
                 unsigned short* __restrict__ ws16, float* __restrict__ wsf)
{
  const int tid = blockIdx.x*256 + threadIdx.x;
  const int stride = gridDim.x*256;
  for (int idx=tid; idx<64*128; idx+=stride){        // [n][k] <- [k][n]
    int n=idx>>7, k=idx&127;
    ws16[AW1T+idx]=f2bu(aW1[k*64+n]);
    ws16[TW1T+idx]=f2bu(tW1[k*64+n]);
    ws16[CW1T+idx]=f2bu(cW1[k*64+n]);
  }
  for (int idx=tid; idx<64*64; idx+=stride){
    int n=idx>>6, k=idx&63;
    ws16[AW2T+idx]=f2bu(aW2[k*64+n]);
    ws16[TW2T+idx]=f2bu(tW2[k*64+n]);
    ws16[CW2T+idx]=f2bu(cW2[k*64+n]);
  }
  for (int idx=tid; idx<16*64; idx+=stride){
    int n=idx>>6, k=idx&63;
    ws16[MWT+idx]=f2bu(n<8 ? mW[k*8+n] : 0.f);
  }
  for (int idx=tid; idx<48*64; idx+=stride){         // diag-first row permutation
    int n=idx>>6, k=idx&63;
    ws16[HWT+idx]=f2bu(n<36 ? hW[k*36+PERM[n]] : 0.f);
  }
  for (int idx=tid; idx<4*32*128; idx+=stride){      // fW1 x-part
    int i=idx>>12, rem=idx&4095, n=rem>>7, k=rem&127;
    ws16[FW1XT+idx]=f2bu(fW1[i*4224 + (4+k)*32 + n]);
  }
  for (int idx=tid; idx<4*16*32; idx+=stride){
    int i=idx>>9, rem=idx&511, n=rem>>5, k=rem&31;
    ws16[FW2T+idx]=f2bu(n<8 ? fW2[i*256 + k*8 + n] : 0.f);
  }
  for (int idx=tid; idx<4*32*4; idx+=stride){        // fW1 cond part, fp32 [n][k]
    int i=idx>>7, rem=idx&127, n=rem>>2, k=rem&3;
    wsf[W1CTO+idx]=fW1[i*4224 + k*32 + n];
  }
  for (int idx=tid; idx<48; idx+=stride)
    wsf[HBPO+idx] = idx<36 ? hb[PERM[idx]] : 0.f;
}

// ============ GEMM helpers (outputs transposed: rows=neurons, cols=elems) ===
template<int NWT>
__device__ __forceinline__ void gemmX(const unsigned short* __restrict__ Wt,
                                      const v8s* __restrict__ xf,
                                      f4 (*acc)[4], int c, int q)
{
#pragma unroll
  for (int kt=0; kt<4; ++kt){
    v8s wf[NWT];
#pragma unroll
    for (int wt=0; wt<NWT; ++wt)
      wf[wt] = *(const v8s*)(Wt + (wt*16 + c)*128 + kt*32 + q*8);
#pragma unroll
    for (int wt=0; wt<NWT; ++wt)
#pragma unroll
      for (int et=0; et<4; ++et)
        acc[wt][et] = MFMA16(wf[wt], xf[et*4+kt], acc[wt][et], 0,0,0);
  }
}

template<int NWT>
__device__ __forceinline__ void gemmH(const unsigned short* __restrict__ Wt,
                                      const unsigned short* __restrict__ actL,
                                      f4 (*acc)[4], int c, int q)
{
#pragma unroll
  for (int kt=0; kt<2; ++kt){
    v8s wf[NWT];
#pragma unroll
    for (int wt=0; wt<NWT; ++wt)
      wf[wt] = *(const v8s*)(Wt + (wt*16 + c)*64 + kt*32 + q*8);
    v8s af[4];
#pragma unroll
    for (int et=0; et<4; ++et)
      af[et] = *(const v8s*)(actL + swz(et*16+c, kt*4+q));
#pragma unroll
    for (int wt=0; wt<NWT; ++wt)
#pragma unroll
      for (int et=0; et<4; ++et)
        acc[wt][et] = MFMA16(wf[wt], af[et], acc[wt][et], 0,0,0);
  }
}

// ============ main: 64 elements per wave, 1 wave/block, no barriers ============
__global__ __launch_bounds__(64,4)
void policy_kernel(
    const float* __restrict__ x,    const float* __restrict__ action, const float* __restrict__ z_rpo,
    const float* __restrict__ cb1,  const float* __restrict__ c_rms,  const float* __restrict__ cb2,
    const float* __restrict__ cW3,  const float* __restrict__ cb3,
    const float* __restrict__ ab1,  const float* __restrict__ ab2,    const float* __restrict__ mb,
    const float* __restrict__ tb1,  const float* __restrict__ t_rms1, const float* __restrict__ tb2,
    const float* __restrict__ t_rms2,
    const float* __restrict__ fb1,  const float* __restrict__ fb2,
    const unsigned short* __restrict__ ws16, const float* __restrict__ wsf,
    float* __restrict__ out, const int Btot)
{
  const int lane = threadIdx.x;
  const int q = lane >> 4, c = lane & 15;
  const int b0 = blockIdx.x << 6;

  __shared__ alignas(16) unsigned char smem[15872];
  unsigned short* actL = (unsigned short*)smem;            // [64][64] bf16, XOR-swizzled (hidL aliases)
  unsigned short* hidL = (unsigned short*)smem;
  unsigned short* triL = (unsigned short*)(smem + 8192);   // [64][36] bf16
  float*          nstL = (float*)(smem + 12800);           // [64][8] f32
  unsigned short* amL  = (unsigned short*)(smem + 14848);  // [64][8] bf16 (st aliases)

  // ---- resident x fragments: xf[et*4+kt] = x[et*16+c][kt*32+q*8 ..+8] ----
  v8s xf[16];
  {
    const float* xb = x + (size_t)b0*128;
#pragma unroll
    for (int et=0; et<4; ++et)
#pragma unroll
      for (int kt=0; kt<4; ++kt){
        const float* p = xb + (size_t)(et*16+c)*128 + kt*32 + q*8;
        f4 u0 = *(const f4*)p, u1 = *(const f4*)(p+4);
        union { unsigned u[4]; v8s v; } r;
        r.u[0]=pk2(u0[0],u0[1]); r.u[1]=pk2(u0[2],u0[3]);
        r.u[2]=pk2(u1[0],u1[1]); r.u[3]=pk2(u1[2],u1[3]);
        xf[et*4+kt] = r.v;
      }
  }

  f4 acc[4][4];
  const f4 z4 = {0.f,0.f,0.f,0.f};

  // =================== actor ===================
#pragma unroll
  for (int wt=0; wt<4; ++wt) for (int et=0; et<4; ++et) acc[wt][et]=z4;
  gemmX<4>(ws16+AW1T, xf, acc, c, q);
#pragma unroll
  for (int wt=0; wt<4; ++wt){
    const f4 bv = *(const f4*)(ab1 + wt*16 + q*4);
#pragma unroll
    for (int et=0; et<4; ++et){
      float s0=siluf(acc[wt][et][0]+bv[0]), s1=siluf(acc[wt][et][1]+bv[1]);
      float s2=siluf(acc[wt][et][2]+bv[2]), s3=siluf(acc[wt][et][3]+bv[3]);
      u32x2 u = {pk2(s0,s1), pk2(s2,s3)};
      *(u32x2*)(actL + swz(et*16+c, wt*2+(q>>1)) + (q&1)*4) = u;
    }
  }
#pragma unroll
  for (int wt=0; wt<4; ++wt) for (int et=0; et<4; ++et) acc[wt][et]=z4;
  gemmH<4>(ws16+AW2T, actL, acc, c, q);
#pragma unroll
  for (int wt=0; wt<4; ++wt){
    const f4 bv = *(const f4*)(ab2 + wt*16 + q*4);
#pragma unroll
    for (int et=0; et<4; ++et){
      float s0=siluf(acc[wt][et][0]+bv[0]), s1=siluf(acc[wt][et][1]+bv[1]);
      float s2=siluf(acc[wt][et][2]+bv[2]), s3=siluf(acc[wt][et][3]+bv[3]);
      u32x2 u = {pk2(s0,s1), pk2(s2,s3)};
      *(u32x2*)(actL + swz(et*16+c, wt*2+(q>>1)) + (q&1)*4) = u;
    }
  }
  {
    f4 am1[1][4]; am1[0][0]=z4; am1[0][1]=z4; am1[0][2]=z4; am1[0][3]=z4;
    gemmH<1>(ws16+MWT, actL, am1, c, q);
    if (q<2){
      const f4 mbv = *(const f4*)(mb + q*4);
#pragma unroll
      for (int et=0; et<4; ++et){
        u32x2 u = {pk2(am1[0][et][0]+mbv[0], am1[0][et][1]+mbv[1]),
                   pk2(am1[0][et][2]+mbv[2], am1[0][et][3]+mbv[3])};
        *(u32x2*)(amL + (et*16+c)*8 + q*4) = u;
      }
    }
  }

  // =================== t branch ===================
#pragma unroll
  for (int wt=0; wt<4; ++wt) for (int et=0; et<4; ++et) acc[wt][et]=z4;
  gemmX<4>(ws16+TW1T, xf, acc, c, q);
  float r1[4];
  {
    float ss[4]={0.f,0.f,0.f,0.f};
#pragma unroll
    for (int wt=0; wt<4; ++wt){
      const f4 bv = *(const f4*)(tb1 + wt*16 + q*4);
      const f4 rw = *(const f4*)(t_rms1 + wt*16 + q*4);
#pragma unroll
      for (int et=0; et<4; ++et){
        float s0=siluf(acc[wt][et][0]+bv[0]), s1=siluf(acc[wt][et][1]+bv[1]);
        float s2=siluf(acc[wt][et][2]+bv[2]), s3=siluf(acc[wt][et][3]+bv[3]);
        ss[et] += s0*s0+s1*s1+s2*s2+s3*s3;
        u32x2 u = {pk2(s0*rw[0],s1*rw[1]), pk2(s2*rw[2],s3*rw[3])};
        *(u32x2*)(actL + swz(et*16+c, wt*2+(q>>1)) + (q&1)*4) = u;
      }
    }
#pragma unroll
    for (int et=0; et<4; ++et) r1[et]=rsqrtf(qsum(ss[et])*(1.f/64.f)+EPSF);
  }
#pragma unroll
  for (int wt=0; wt<4; ++wt) for (int et=0; et<4; ++et) acc[wt][et]=z4;
  gemmH<4>(ws16+TW2T, actL, acc, c, q);
  float r2[4];
  {
    float ss[4]={0.f,0.f,0.f,0.f};
#pragma unroll
    for (int wt=0; wt<4; ++wt){
      const f4 bv = *(const f4*)(tb2 + wt*16 + q*4);
      const f4 rw = *(const f4*)(t_rms2 + wt*16 + q*4);
#pragma unroll
      for (int et=0; et<4; ++et){
        float s0=siluf(r1[et]*acc[wt][et][0]+bv[0]), s1=siluf(r1[et]*acc[wt][et][1]+bv[1]);
        float s2=siluf(r1[et]*acc[wt][et][2]+bv[2]), s3=siluf(r1[et]*acc[wt][et][3]+bv[3]);
        ss[et] += s0*s0+s1*s1+s2*s2+s3*s3;
        u32x2 u = {pk2(s0*rw[0],s1*rw[1]), pk2(s2*rw[2],s3*rw[3])};
        *(u32x2*)(actL + swz(et*16+c, wt*2+(q>>1)) + (q&1)*4) = u;
      }
    }
#pragma unroll
    for (int et=0; et<4; ++et) r2[et]=rsqrtf(qsum(ss[et])*(1.f/64.f)+EPSF);
  }
  // Cholesky head (rows permuted diag-first; diag = rows 0..7 = wt0, q<2)
  float ldet[4];
  {
    f4 a3[3][4];
#pragma unroll
    for (int wt=0; wt<3; ++wt) for (int et=0; et<4; ++et) a3[wt][et]=z4;
    gemmH<3>(ws16+HWT, actL, a3, c, q);
    float ldp[4]={0.f,0.f,0.f,0.f};
#pragma unroll
    for (int wt=0; wt<3; ++wt){
      const f4 hbv = *(const f4*)(wsf + HBPO + wt*16 + q*4);
#pragma unroll
      for (int et=0; et<4; ++et){
        float t0=r2[et]*a3[wt][et][0]+hbv[0], t1=r2[et]*a3[wt][et][1]+hbv[1];
        float t2=r2[et]*a3[wt][et][2]+hbv[2], t3=r2[et]*a3[wt][et][3]+hbv[3];
        if (wt==0 && q<2){
          t0=fmaxf(t0,0.f)+__logf(1.f+__expf(-fabsf(t0)));
          t1=fmaxf(t1,0.f)+__logf(1.f+__expf(-fabsf(t1)));
          t2=fmaxf(t2,0.f)+__logf(1.f+__expf(-fabsf(t2)));
          t3=fmaxf(t3,0.f)+__logf(1.f+__expf(-fabsf(t3)));
          ldp[et] += __logf(t0)+__logf(t1)+__logf(t2)+__logf(t3);
        }
        if (wt<2 || q==0){
          u32x2 u = {pk2(t0,t1), pk2(t2,t3)};
          *(u32x2*)(triL + (et*16+c)*36 + wt*16 + q*4) = u;
        }
      }
    }
#pragma unroll
    for (int et=0; et<4; ++et) ldet[et]=qsum(ldp[et]);
  }

  // =================== critic ===================
#pragma unroll
  for (int wt=0; wt<4; ++wt) for (int et=0; et<4; ++et) acc[wt][et]=z4;
  gemmX<4>(ws16+CW1T, xf, acc, c, q);
  float rc[4];
  {
    float ss[4]={0.f,0.f,0.f,0.f};
#pragma unroll
    for (int wt=0; wt<4; ++wt){
      const f4 bv = *(const f4*)(cb1 + wt*16 + q*4);
      const f4 rw = *(const f4*)(c_rms + wt*16 + q*4);
#pragma unroll
      for (int et=0; et<4; ++et){
        float s0=siluf(acc[wt][et][0]+bv[0]), s1=siluf(acc[wt][et][1]+bv[1]);
        float s2=siluf(acc[wt][et][2]+bv[2]), s3=siluf(acc[wt][et][3]+bv[3]);
        ss[et] += s0*s0+s1*s1+s2*s2+s3*s3;
        u32x2 u = {pk2(s0*rw[0],s1*rw[1]), pk2(s2*rw[2],s3*rw[3])};
        *(u32x2*)(actL + swz(et*16+c, wt*2+(q>>1)) + (q&1)*4) = u;
      }
    }
#pragma unroll
    for (int et=0; et<4; ++et) rc[et]=rsqrtf(qsum(ss[et])*(1.f/64.f)+EPSF);
  }
  float vv[4];
  {
#pragma unroll
    for (int wt=0; wt<4; ++wt) for (int et=0; et<4; ++et) acc[wt][et]=z4;
    gemmH<4>(ws16+CW2T, actL, acc, c, q);
    float vp[4]={0.f,0.f,0.f,0.f};
#pragma unroll
    for (int wt=0; wt<4; ++wt){
      const f4 bv = *(const f4*)(cb2 + wt*16 + q*4);
      const f4 wv = *(const f4*)(cW3 + wt*16 + q*4);
#pragma unroll
      for (int et=0; et<4; ++et){
        vp[et] = fmaf(siluf(rc[et]*acc[wt][et][0]+bv[0]), wv[0], vp[et]);
        vp[et] = fmaf(siluf(rc[et]*acc[wt][et][1]+bv[1]), wv[1], vp[et]);
        vp[et] = fmaf(siluf(rc[et]*acc[wt][et][2]+bv[2]), wv[2], vp[et]);
        vp[et] = fmaf(siluf(rc[et]*acc[wt][et][3]+bv[3]), wv[3], vp[et]);
      }
    }
    const float cb3v = cb3[0];
#pragma unroll
    for (int et=0; et<4; ++et) vv[et]=qsum(vp[et])+cb3v;
  }

  // =================== per-element: nst, action passthrough ===================
  const int l = lane;
  const size_t bb = (size_t)(b0+l)*8;
  float nst[8], fld=0.f;
  {
    f4 a0=*(const f4*)(action+bb), a1=*(const f4*)(action+bb+4);
    f4 zr0=*(const f4*)(z_rpo+bb), zr1=*(const f4*)(z_rpo+bb+4);
    *(f4*)(out+bb)=a0; *(f4*)(out+bb+4)=a1;
#pragma unroll
    for (int j=0;j<4;++j){
      nst[j]   = a0[j]-b2f16(amL[l*8+j])  -zr0[j];
      nst[4+j] = a1[j]-b2f16(amL[l*8+4+j])-zr1[j];
    }
    *(f4*)(nstL + l*8)     = (f4){nst[0],nst[1],nst[2],nst[3]};
    *(f4*)(nstL + l*8 + 4) = (f4){nst[4],nst[5],nst[6],nst[7]};
  }

  // =================== flow (hidL aliases actL; stL aliases amL) ===================
#pragma unroll
  for (int ii=0; ii<4; ++ii){
    const int i = 3-ii;
    const int cb = (i&1)?4:0, yb = (i&1)?0:4;
    f4 a2[2][4];
#pragma unroll
    for (int wt=0; wt<2; ++wt) for (int et=0; et<4; ++et) a2[wt][et]=z4;
    gemmX<2>(ws16+FW1XT+i*4096, xf, a2, c, q);
    float nv[4][4];
#pragma unroll
    for (int et=0; et<4; ++et){
      const float* np = nstL + (et*16+c)*8 + cb;
      f2 t0=*(const f2*)np, t1=*(const f2*)(np+2);
      nv[et][0]=t0[0]; nv[et][1]=t0[1]; nv[et][2]=t1[0]; nv[et][3]=t1[1];
    }
#pragma unroll
    for (int wt=0; wt<2; ++wt){
      const f4 bv = *(const f4*)(fb1 + i*32 + wt*16 + q*4);
      float sh[4][4];
#pragma unroll
      for (int r=0; r<4; ++r){
        const f4 wc = *(const f4*)(wsf + W1CTO + i*128 + (wt*16+q*4+r)*4);
#pragma unroll
        for (int et=0; et<4; ++et){
          float hv = a2[wt][et][r] + bv[r]
                   + wc[0]*nv[et][0] + wc[1]*nv[et][1]
                   + wc[2]*nv[et][2] + wc[3]*nv[et][3];
          sh[et][r] = siluf(hv);
        }
      }
#pragma unroll
      for (int et=0; et<4; ++et){
        u32x2 u = {pk2(sh[et][0],sh[et][1]), pk2(sh[et][2],sh[et][3])};
        *(u32x2*)(hidL + swz(et*16+c, wt*2+(q>>1)) + (q&1)*4) = u;
      }
    }
    // second flow layer: st = silu(hid) @ fW2 + fb2
    {
      const v8s wf3 = *(const v8s*)(ws16 + FW2T + i*512 + c*32 + q*8);
      f4 as[4];
#pragma unroll
      for (int et=0; et<4; ++et){
        const v8s hf = *(const v8s*)(hidL + swz(et*16+c, q));
        f4 a1s = z4;
        a1s = MFMA16(wf3, hf, a1s, 0,0,0);
        as[et]=a1s;
      }
      if (q<2){
        const f4 fbv = *(const f4*)(fb2 + i*8 + q*4);
#pragma unroll
        for (int et=0; et<4; ++et){
          u32x2 u = {pk2(as[et][0]+fbv[0], as[et][1]+fbv[1]),
                     pk2(as[et][2]+fbv[2], as[et][3]+fbv[3])};
          *(u32x2*)(amL + (et*16+c)*8 + q*4) = u;   // stL
        }
      }
    }
    // per-element update
    {
      float sr0=b2f16(amL[l*8+0]), sr1=b2f16(amL[l*8+1]);
      float sr2=b2f16(amL[l*8+2]), sr3=b2f16(amL[l*8+3]);
      float th0=b2f16(amL[l*8+4]), th1=b2f16(amL[l*8+5]);
      float th2=b2f16(amL[l*8+6]), th3=b2f16(amL[l*8+7]);
      float s0=2.f-4.f*rcpf(__expf(2.f*sr0)+1.f);
      float s1=2.f-4.f*rcpf(__expf(2.f*sr1)+1.f);
      float s2=2.f-4.f*rcpf(__expf(2.f*sr2)+1.f);
      float s3=2.f-4.f*rcpf(__expf(2.f*sr3)+1.f);
      nst[yb+0]=(nst[yb+0]-th0)*__expf(-s0);
      nst[yb+1]=(nst[yb+1]-th1)*__expf(-s1);
      nst[yb+2]=(nst[yb+2]-th2)*__expf(-s2);
      nst[yb+3]=(nst[yb+3]-th3)*__expf(-s3);
      *(f4*)(nstL + l*8 + yb) = (f4){nst[yb+0],nst[yb+1],nst[yb+2],nst[yb+3]};
      fld += s0+s1+s2+s3;
    }
  }

  // =================== triangular solve + outputs ===================
  {
    constexpr int INVPERM[36] = {0,8,1,9,10,2,11,12,13,3,14,15,16,17,4,18,19,20,
                                 21,22,5,23,24,25,26,27,28,6,29,30,31,32,33,34,35,7};
    float tri[36];
#pragma unroll
    for (int j=0;j<36;++j) tri[j] = b2f16(triL[l*36 + INVPERM[j]]);
    float zv[8], mahal=0.f;
#pragma unroll
    for (int r=0;r<8;++r){
      float s=nst[r];
      const int base=(r*(r+1))>>1;
#pragma unroll
      for (int cc=0;cc<r;++cc) s -= tri[base+cc]*zv[cc];
      const float z = s*rcpf(tri[base+r]);
      zv[r]=z; mahal+=z*z;
    }
    const float ldet_s = (l<16)?ldet[0]:(l<32)?ldet[1]:(l<48)?ldet[2]:ldet[3];
    const float v_s    = (l<16)?vv[0]:(l<32)?vv[1]:(l<48)?vv[2]:vv[3];
    const float lp = -0.5f*(8.f*LOG2PI+mahal) - ldet_s - fld;
    const float en =  0.5f*(8.f*(1.f+LOG2PI)) + ldet_s + fld;
    out[(size_t)Btot*8  + b0 + l] = lp;
    out[(size_t)Btot*9  + b0 + l] = en;
    out[(size_t)Btot*10 + b0 + l] = v_s;
  }
}

extern "C" void kernel_launch(void* const* d_in, const int* in_sizes, int n_in,
                              void* d_out, int out_size, void* d_ws, size_t ws_size,
                              hipStream_t stream) {
  const float* x      = (const float*)d_in[0];
  const float* action = (const float*)d_in[1];
  const float* z_rpo  = (const float*)d_in[2];
  const float* cW1    = (const float*)d_in[3];
  const float* cb1    = (const float*)d_in[4];
  const float* c_rms  = (const float*)d_in[5];
  const float* cW2    = (const float*)d_in[6];
  const float* cb2    = (const float*)d_in[7];
  const float* cW3    = (const float*)d_in[8];
  const float* cb3    = (const float*)d_in[9];
  const float* aW1    = (const float*)d_in[10];
  const float* ab1    = (const float*)d_in[11];
  const float* aW2    = (const float*)d_in[12];
  const float* ab2    = (const float*)d_in[13];
  const float* mW     = (const float*)d_in[14];
  const float* mb     = (const float*)d_in[15];
  const float* tW1    = (const float*)d_in[16];
  const float* tb1    = (const float*)d_in[17];
  const float* t_rms1 = (const float*)d_in[18];
  const float* tW2    = (const float*)d_in[19];
  const float* tb2    = (const float*)d_in[20];
  const float* t_rms2 = (const float*)d_in[21];
  const float* hW     = (const float*)d_in[22];
  const float* hb     = (const float*)d_in[23];
  const float* fW1    = (const float*)d_in[24];
  const float* fb1    = (const float*)d_in[25];
  const float* fW2    = (const float*)d_in[26];
  const float* fb2    = (const float*)d_in[27];
  float* out = (float*)d_out;

  unsigned short* ws16 = (unsigned short*)d_ws;
  float* wsf = (float*)((char*)d_ws + WS_BF16_TOTAL*2);

  const int Btot = in_sizes[0] / 128;   // 131072

  hipLaunchKernelGGL(prep_kernel, dim3(128), dim3(256), 0, stream,
                     aW1, aW2, mW, tW1, tW2, hW, hb, cW1, cW2, fW1, fW2, ws16, wsf);
  hipLaunchKernelGGL(policy_kernel, dim3(Btot/64), dim3(64), 0, stream,
                     x, action, z_rpo, cb1, c_rms, cb2, cW3, cb3,
                     ab1, ab2, mb, tb1, t_rms1, tb2, t_rms2, fb1, fb2,
                     ws16, wsf, out, Btot);
}